// Round 6
// baseline (131.316 us; speedup 1.0000x reference)
//
#include <hip/hip_runtime.h>
#include <hip/hip_bf16.h>
#include <math.h>

#define NB 32768
#define DD 128
#define HH 512
#define EE 16
#define TM 64
#define HC 64
#define NCH (HH / HC)

typedef __attribute__((ext_vector_type(8))) short short8;
typedef __attribute__((ext_vector_type(4))) float f32x4;
typedef __attribute__((address_space(1))) const unsigned short gc_us;
typedef __attribute__((address_space(3))) unsigned short lds_us;

__device__ __forceinline__ unsigned short f2bf(float f) {
  union { float f; unsigned u; } v; v.f = f;
  unsigned r = v.u + 0x7fffu + ((v.u >> 16) & 1u);
  return (unsigned short)(r >> 16);
}

// Abramowitz-Stegun 7.1.26 erf, |eps| <= 1.5e-7; v_rcp (1 ULP) instead of IEEE div
__device__ __forceinline__ float fast_erf(float z) {
  float a = fabsf(z);
  float t = __builtin_amdgcn_rcpf(1.0f + 0.3275911f * a);
  float y = t * (0.254829592f + t * (-0.284496736f + t * (1.421413741f +
            t * (-1.453152027f + t * 1.061405429f))));
  float r = 1.0f - y * __expf(-a * a);
  return z < 0.0f ? -r : r;
}

// ---------------- fused prep: gate (blocks 0..511) + weight transpose (512..1023) ----------
__global__ __launch_bounds__(256) void prep_kernel(
    const float* __restrict__ x, const float* __restrict__ wg,
    const float* __restrict__ bg, const float* __restrict__ w1,
    const float* __restrict__ w2, int* __restrict__ counts,
    int* __restrict__ rows, unsigned short* __restrict__ w1T,
    unsigned short* __restrict__ w2T) {
  __shared__ __align__(16) char smem[50816];
  int tid = threadIdx.x;

  if (blockIdx.x >= 512) {
    // ---- 64x64 fp32 tile transpose -> bf16 ----
    float (*tile)[65] = (float (*)[65])smem;
    int tp = blockIdx.x - 512;
    const float* src; unsigned short* dst; int S, Sd;
    if (tp < 256) {
      int e = tp >> 4, t2 = tp & 15;
      int d0 = (t2 >> 3) * 64, h0 = (t2 & 7) * 64;
      src = w1 + (size_t)e * DD * HH + (size_t)d0 * HH + h0; S = HH;
      dst = w1T + (size_t)e * HH * DD + (size_t)h0 * DD + d0; Sd = DD;
    } else {
      int t = tp - 256;
      int e = t >> 4, t2 = t & 15;
      int h0 = (t2 >> 1) * 64, d0 = (t2 & 1) * 64;
      src = w2 + (size_t)e * HH * DD + (size_t)h0 * DD + d0; S = DD;
      dst = w2T + (size_t)e * DD * HH + (size_t)d0 * HH + h0; Sd = HH;
    }
    #pragma unroll
    for (int i = 0; i < 4; ++i) {
      int u = tid + i * 256, r = u >> 4, c = (u & 15) * 4;
      float4 v = *(const float4*)(src + (size_t)r * S + c);
      tile[r][c + 0] = v.x; tile[r][c + 1] = v.y;
      tile[r][c + 2] = v.z; tile[r][c + 3] = v.w;
    }
    __syncthreads();
    #pragma unroll
    for (int i = 0; i < 4; ++i) {
      int u = tid + i * 256, tr = u >> 4, tc = (u & 15) * 4;
      ushort4 p;
      p.x = f2bf(tile[tc + 0][tr]); p.y = f2bf(tile[tc + 1][tr]);
      p.z = f2bf(tile[tc + 2][tr]); p.w = f2bf(tile[tc + 3][tr]);
      *(ushort4*)(dst + (size_t)tr * Sd + tc) = p;
    }
    return;
  }

  // ---- gating: fp64 logits + block-aggregated bucket scatter ----
  float  (*sx)[132] = (float (*)[132])smem;
  double (*swg)[EE] = (double (*)[EE])(smem + 33792);
  int* lcnt  = (int*)(smem + 50176);
  int* gbase = lcnt + EE;
  int* lslot = gbase + EE;
  int* lexp  = lslot + 64;

  int base = blockIdx.x * 64;
  if (tid < EE) lcnt[tid] = 0;
  for (int i = tid; i < DD * EE; i += 256) swg[i >> 4][i & 15] = (double)wg[i];
  {
    int r = tid >> 2, c0 = (tid & 3) * 32;
    const float4* src = (const float4*)(x + (size_t)(base + r) * DD + c0);
    #pragma unroll
    for (int i = 0; i < 8; ++i)
      *(float4*)&sx[r][c0 + i * 4] = src[i];
  }
  __syncthreads();

  int r = tid >> 2;
  int e0 = (tid & 3) * 4;
  double acc[4];
  #pragma unroll
  for (int j = 0; j < 4; ++j) acc[j] = (double)bg[e0 + j];

  #pragma unroll 4
  for (int d = 0; d < DD; ++d) {
    double xv = (double)sx[r][d];
    #pragma unroll
    for (int j = 0; j < 4; ++j)
      acc[j] += xv * swg[d][e0 + j];
  }

  int beste = 0; double bestv = acc[0];
  #pragma unroll
  for (int j = 1; j < 4; ++j)
    if (acc[j] > bestv) { bestv = acc[j]; beste = j; }
  int ge = e0 + beste;

  #pragma unroll
  for (int off = 1; off < 4; off <<= 1) {
    double ov = __shfl_xor(bestv, off);
    int oe = __shfl_xor(ge, off);
    if (ov > bestv || (ov == bestv && oe < ge)) { bestv = ov; ge = oe; }
  }

  if ((tid & 3) == 0) {
    lslot[r] = atomicAdd(&lcnt[ge], 1);
    lexp[r] = ge;
  }
  __syncthreads();
  if (tid < EE && lcnt[tid] > 0)
    gbase[tid] = atomicAdd(&counts[tid], lcnt[tid]);
  __syncthreads();
  if ((tid & 3) == 0) {
    int e2 = lexp[r];
    rows[e2 * NB + gbase[e2] + lslot[r]] = base + r;
  }
}

// ---------------- grouped expert GEMM: out[r] = gelu(x[r]@w1[e]) @ w2[e] ----------------
// v7 = R4's DMA/compute overlap + R5's 16 waves/CU + half the staging traffic.
//   512 threads, TM=64, wave = (rg = wv&3 row-group, hf = wv>>2 H-half). Per-wave work
//   equals v6; weight traffic halves (512 blocks x 256 KB); weights double-buffered so
//   chunk hc+1's global_load_lds DMA flies under chunk hc's MFMA+gelu; ONE barrier/chunk.
//   LDS 74.75 KB -> 2 blocks/CU -> 16 waves/CU WITH overlap.
// Staging geometry + swizzle byte-identical to HW-verified v5/v6 (waves 0-3 stage sW1,
// waves 4-7 stage sW2). Layout invariant: element (row,col) of [R][C]-short tile at
//   row*C + ((col>>3) ^ (row&7))*8 + (col&7),  C=128 (sW1), C=64 (sW2).
__global__ __launch_bounds__(512, 4) void moe_gemm(
    const float* __restrict__ x, const unsigned short* __restrict__ w1T,
    const unsigned short* __restrict__ w2T, const int* __restrict__ counts,
    const int* __restrict__ rows, float* __restrict__ out) {
  int e = blockIdx.x;
  int cnt = counts[e];
  int base = blockIdx.y * TM;
  if (base >= cnt) return;

  // carve one LDS arena: sW1[2][8192] | sW2[2][8192] | sH[64*72]   (74752 B)
  __shared__ __align__(16) unsigned short smem[37376];
  unsigned short* sW1 = smem;                 // 2 bufs x 8192 shorts
  unsigned short* sW2 = smem + 16384;         // 2 bufs x 8192 shorts
  unsigned short* sH  = smem + 32768;         // [64][72], wave-private rows x col-half

  int tid = threadIdx.x;
  int wv = tid >> 6, l = tid & 63;
  int lm = l & 15, q = l >> 4;
  int rg = wv & 3;       // row group: rows [rg*16, rg*16+16)
  int hf = wv >> 2;      // H half:    h in [hf*32, hf*32+32) of each 64-chunk

  const unsigned short* w1e = w1T + (size_t)e * HH * DD;
  const unsigned short* w2e = w2T + (size_t)e * DD * HH;

  // X A-fragments in registers: xa[ks] holds X[m = rg*16+lm][k = ks*32 + q*8 + j]
  short8 xa[4];
  {
    int ridx = base + rg * 16 + lm; if (ridx >= cnt) ridx = cnt - 1;
    int grow = rows[e * NB + ridx];
    const float* xr = x + (size_t)grow * DD + q * 8;
    #pragma unroll
    for (int ks = 0; ks < 4; ++ks) {
      f32x4 v0 = *(const f32x4*)(xr + ks * 32);
      f32x4 v1 = *(const f32x4*)(xr + ks * 32 + 4);
      short8 a;
      a[0] = f2bf(v0[0]); a[1] = f2bf(v0[1]); a[2] = f2bf(v0[2]); a[3] = f2bf(v0[3]);
      a[4] = f2bf(v1[0]); a[5] = f2bf(v1[1]); a[6] = f2bf(v1[2]); a[7] = f2bf(v1[3]);
      xa[ks] = a;
    }
  }

  // direct-to-LDS staging: waves 0-3 own sW1 (4x 1KB DMA), waves 4-7 own sW2
  auto stage_chunk = [&](int buf, int c) {
    if (wv < 4) {
      const unsigned short* w1c = w1e + (size_t)c * HC * DD;
      #pragma unroll
      for (int i = 0; i < 4; ++i) {
        int r = wv * 16 + i * 4 + (l >> 4);
        const unsigned short* g = w1c + (size_t)r * DD + (((l & 15) ^ (r & 7)) << 3);
        __builtin_amdgcn_global_load_lds((gc_us*)g,
            (lds_us*)(sW1 + buf * 8192 + wv * 2048 + i * 512), 16, 0, 0);
      }
    } else {
      int wz = wv - 4;
      const unsigned short* w2c = w2e + (size_t)c * HC;
      #pragma unroll
      for (int i = 0; i < 4; ++i) {
        int r = wz * 32 + i * 8 + (l >> 3);
        const unsigned short* g = w2c + (size_t)r * HH + (((l & 7) ^ (r & 7)) << 3);
        __builtin_amdgcn_global_load_lds((gc_us*)g,
            (lds_us*)(sW2 + buf * 8192 + wz * 2048 + i * 512), 16, 0, 0);
      }
    }
  };

  stage_chunk(0, 0);
  __syncthreads();

  f32x4 acc2[8];
  #pragma unroll
  for (int n = 0; n < 8; ++n) acc2[n] = (f32x4){0.f, 0.f, 0.f, 0.f};

  for (int hc = 0; hc < NCH; ++hc) {
    int b = hc & 1;

    // issue next chunk's DMA into the other buffer; lands during this chunk's compute
    if (hc + 1 < NCH) stage_chunk(b ^ 1, hc + 1);

    // GEMM1: hidden(16 rows x 32 h per wave) = X(16x128, regs) @ W1chunk[:, hf-half]
    f32x4 acc1[2];
    #pragma unroll
    for (int n = 0; n < 2; ++n) acc1[n] = (f32x4){0.f, 0.f, 0.f, 0.f};
    #pragma unroll
    for (int ks = 0; ks < 4; ++ks) {
      #pragma unroll
      for (int n = 0; n < 2; ++n) {
        int row = hf * 32 + n * 16 + lm;
        int sl = ((ks * 4 + q) ^ (row & 7)) * 8;
        short8 bfr = *(const short8*)&sW1[b * 8192 + row * DD + sl];
        acc1[n] = __builtin_amdgcn_mfma_f32_16x16x32_bf16(xa[ks], bfr, acc1[n], 0, 0, 0);
      }
    }
    // gelu -> bf16 -> sH (wave-private region rows rg*16.., col-half hf; lgkmcnt orders RAW)
    #pragma unroll
    for (int n = 0; n < 2; ++n) {
      #pragma unroll
      for (int rr = 0; rr < 4; ++rr) {
        float v = acc1[n][rr];
        float g = 0.5f * v * (1.0f + fast_erf(v * 0.70710678118654752f));
        sH[(rg * 16 + q * 4 + rr) * 72 + hf * 32 + n * 16 + lm] = f2bf(g);
      }
    }
    // GEMM2 partial: out(16x128 per wave) += H(16 x 32-k half) @ W2chunk[hf-half, :]
    {
      short8 a = *(const short8*)&sH[(rg * 16 + lm) * 72 + hf * 32 + q * 8];
      #pragma unroll
      for (int n = 0; n < 8; ++n) {
        int row = n * 16 + lm;
        int sl = ((hf * 4 + q) ^ (row & 7)) * 8;
        short8 bfr = *(const short8*)&sW2[b * 8192 + row * HC + sl];
        acc2[n] = __builtin_amdgcn_mfma_f32_16x16x32_bf16(a, bfr, acc2[n], 0, 0, 0);
      }
    }

    __syncthreads();  // all waves done with buf b; next chunk's DMA drained (full compute
                      // phase of flight time); sW scratch reuse in epilogue safe after loop
  }

  // ---- epilogue: sum H-half partials via LDS (weights dead; reuse as fp32 scratch) ----
  float* sc = (float*)smem;   // [64][132] fp32 = 33792 B inside the 64 KB weight region
  if (hf == 1) {
    #pragma unroll
    for (int n = 0; n < 8; ++n)
      #pragma unroll
      for (int rr = 0; rr < 4; ++rr)
        sc[(rg * 16 + q * 4 + rr) * 132 + n * 16 + lm] = acc2[n][rr];
  }
  __syncthreads();
  if (hf == 0) {
    #pragma unroll
    for (int rr = 0; rr < 4; ++rr) {
      int ml = rg * 16 + q * 4 + rr;
      int ridx = base + ml;
      if (ridx < cnt) {
        int grow = rows[e * NB + ridx];
        float* op = out + (size_t)grow * DD + lm;
        #pragma unroll
        for (int n = 0; n < 8; ++n)
          op[n * 16] = acc2[n][rr] + sc[(rg * 16 + q * 4 + rr) * 132 + n * 16 + lm];
      }
    }
  }
}

extern "C" void kernel_launch(void* const* d_in, const int* in_sizes, int n_in,
                              void* d_out, int out_size, void* d_ws, size_t ws_size,
                              hipStream_t stream) {
  const float* x  = (const float*)d_in[0];
  const float* w1 = (const float*)d_in[1];
  const float* w2 = (const float*)d_in[2];
  const float* wg = (const float*)d_in[3];
  const float* bg = (const float*)d_in[4];
  float* out = (float*)d_out;

  // workspace: [0,64) counts ; [1024, +2MB) rows ; w1T bf16 2MB ; w2T bf16 2MB
  int* counts = (int*)d_ws;
  int* rows   = (int*)((char*)d_ws + 1024);
  unsigned short* w1T = (unsigned short*)((char*)d_ws + 1024 + (size_t)EE * NB * 4);
  unsigned short* w2T = w1T + (size_t)EE * HH * DD;

  hipMemsetAsync(d_ws, 0, 64, stream);
  hipLaunchKernelGGL(prep_kernel, dim3(1024), dim3(256), 0, stream,
                     x, wg, bg, w1, w2, counts, rows, w1T, w2T);
  hipLaunchKernelGGL(moe_gemm, dim3(EE, NB / TM), dim3(512), 0, stream,
                     x, w1T, w2T, counts, rows, out);
}

// Round 7
// 129.526 us; speedup vs baseline: 1.0138x; 1.0138x over previous
//
#include <hip/hip_runtime.h>
#include <hip/hip_bf16.h>
#include <math.h>

#define NB 32768
#define DD 128
#define HH 512
#define EE 16
#define TM 64
#define HC 64
#define NCH (HH / HC)

typedef __attribute__((ext_vector_type(8))) short short8;
typedef __attribute__((ext_vector_type(4))) float f32x4;
typedef __attribute__((address_space(1))) const unsigned short gc_us;
typedef __attribute__((address_space(3))) unsigned short lds_us;

__device__ __forceinline__ unsigned short f2bf(float f) {
  union { float f; unsigned u; } v; v.f = f;
  unsigned r = v.u + 0x7fffu + ((v.u >> 16) & 1u);
  return (unsigned short)(r >> 16);
}

// Abramowitz-Stegun 7.1.26 erf, |eps| <= 1.5e-7; v_rcp (1 ULP) instead of IEEE div
__device__ __forceinline__ float fast_erf(float z) {
  float a = fabsf(z);
  float t = __builtin_amdgcn_rcpf(1.0f + 0.3275911f * a);
  float y = t * (0.254829592f + t * (-0.284496736f + t * (1.421413741f +
            t * (-1.453152027f + t * 1.061405429f))));
  float r = 1.0f - y * __expf(-a * a);
  return z < 0.0f ? -r : r;
}

// ---------------- fused prep: gate (blocks 0..511) + weight transpose (512..1023) ----------
// w2T gets the sigma h-permutation baked in: w2T[e][d][K] = w2[e][hsig(K)][d],
// hsig(K) = (K & ~31) | ((K&4)<<2) | ((K&24)>>1) | (K&3)   (bit permutation, bijective).
// This matches GEMM1-swapped's output order so gelu+repack is lane-local (no sH).
__global__ __launch_bounds__(256) void prep_kernel(
    const float* __restrict__ x, const float* __restrict__ wg,
    const float* __restrict__ bg, const float* __restrict__ w1,
    const float* __restrict__ w2, int* __restrict__ counts,
    int* __restrict__ rows, unsigned short* __restrict__ w1T,
    unsigned short* __restrict__ w2T) {
  __shared__ __align__(16) char smem[50816];
  int tid = threadIdx.x;

  if (blockIdx.x >= 512) {
    // ---- 64x64 fp32 tile transpose -> bf16 ----
    float (*tile)[65] = (float (*)[65])smem;
    int tp = blockIdx.x - 512;
    const float* src; unsigned short* dst; int S, Sd; int isw2;
    if (tp < 256) {
      int e = tp >> 4, t2 = tp & 15;
      int d0 = (t2 >> 3) * 64, h0 = (t2 & 7) * 64;
      src = w1 + (size_t)e * DD * HH + (size_t)d0 * HH + h0; S = HH;
      dst = w1T + (size_t)e * HH * DD + (size_t)h0 * DD + d0; Sd = DD;
      isw2 = 0;
    } else {
      int t = tp - 256;
      int e = t >> 4, t2 = t & 15;
      int h0 = (t2 >> 1) * 64, d0 = (t2 & 1) * 64;
      src = w2 + (size_t)e * HH * DD + (size_t)h0 * DD + d0; S = DD;
      dst = w2T + (size_t)e * DD * HH + (size_t)d0 * HH + h0; Sd = HH;
      isw2 = 1;
    }
    #pragma unroll
    for (int i = 0; i < 4; ++i) {
      int u = tid + i * 256, r = u >> 4, c = (u & 15) * 4;
      // w2: permute source h-row so stored K-order matches GEMM2's A-frag k-slots
      int rs = isw2 ? ((r & 32) | ((r & 4) << 2) | ((r & 24) >> 1) | (r & 3)) : r;
      float4 v = *(const float4*)(src + (size_t)rs * S + c);
      tile[r][c + 0] = v.x; tile[r][c + 1] = v.y;
      tile[r][c + 2] = v.z; tile[r][c + 3] = v.w;
    }
    __syncthreads();
    #pragma unroll
    for (int i = 0; i < 4; ++i) {
      int u = tid + i * 256, tr = u >> 4, tc = (u & 15) * 4;
      ushort4 p;
      p.x = f2bf(tile[tc + 0][tr]); p.y = f2bf(tile[tc + 1][tr]);
      p.z = f2bf(tile[tc + 2][tr]); p.w = f2bf(tile[tc + 3][tr]);
      *(ushort4*)(dst + (size_t)tr * Sd + tc) = p;
    }
    return;
  }

  // ---- gating: fp64 logits + block-aggregated bucket scatter ----
  float  (*sx)[132] = (float (*)[132])smem;
  double (*swg)[EE] = (double (*)[EE])(smem + 33792);
  int* lcnt  = (int*)(smem + 50176);
  int* gbase = lcnt + EE;
  int* lslot = gbase + EE;
  int* lexp  = lslot + 64;

  int base = blockIdx.x * 64;
  if (tid < EE) lcnt[tid] = 0;
  for (int i = tid; i < DD * EE; i += 256) swg[i >> 4][i & 15] = (double)wg[i];
  {
    int r = tid >> 2, c0 = (tid & 3) * 32;
    const float4* src = (const float4*)(x + (size_t)(base + r) * DD + c0);
    #pragma unroll
    for (int i = 0; i < 8; ++i)
      *(float4*)&sx[r][c0 + i * 4] = src[i];
  }
  __syncthreads();

  int r = tid >> 2;
  int e0 = (tid & 3) * 4;
  double acc[4];
  #pragma unroll
  for (int j = 0; j < 4; ++j) acc[j] = (double)bg[e0 + j];

  #pragma unroll 4
  for (int d = 0; d < DD; ++d) {
    double xv = (double)sx[r][d];
    #pragma unroll
    for (int j = 0; j < 4; ++j)
      acc[j] += xv * swg[d][e0 + j];
  }

  int beste = 0; double bestv = acc[0];
  #pragma unroll
  for (int j = 1; j < 4; ++j)
    if (acc[j] > bestv) { bestv = acc[j]; beste = j; }
  int ge = e0 + beste;

  #pragma unroll
  for (int off = 1; off < 4; off <<= 1) {
    double ov = __shfl_xor(bestv, off);
    int oe = __shfl_xor(ge, off);
    if (ov > bestv || (ov == bestv && oe < ge)) { bestv = ov; ge = oe; }
  }

  if ((tid & 3) == 0) {
    lslot[r] = atomicAdd(&lcnt[ge], 1);
    lexp[r] = ge;
  }
  __syncthreads();
  if (tid < EE && lcnt[tid] > 0)
    gbase[tid] = atomicAdd(&counts[tid], lcnt[tid]);
  __syncthreads();
  if ((tid & 3) == 0) {
    int e2 = lexp[r];
    rows[e2 * NB + gbase[e2] + lslot[r]] = base + r;
  }
}

// ---------------- grouped expert GEMM: out[r] = gelu(x[r]@w1[e]) @ w2[e] ----------------
// v9: sH DELETED via operand-swapped GEMM1 (T12 principle). GEMM1 computes
//     mfma(W1frag, Xfrag) -> H^T tile: lane holds ONE m (col=lm) and 8 h-values
//     (rows q*4+r over n,hf). gelu + bf16 repack is lane-local; ha feeds GEMM2's
//     A-fragment directly (k-slot q*8+j), with the h-order mismatch fixed by the
//     sigma permutation baked into w2T at prep. No LDS round-trip, no lgkmcnt drain
//     between GEMM1 and GEMM2 -> the per-chunk serial chain (R2..R6's shared 45 us
//     floor) collapses to register-only MFMA->VALU->MFMA.
//     Derived mappings (m89-verified layouts):
//       GEMM1 D: acc1[n][r] = H[m=rg*16+lm][h = hf*32+n*16+q*4+r]
//       ha[j] = gelu(acc1[j>>2][j&3])  -> A[m=lm][k=q*8+j], sigma(k)=(j>>2)*16+q*4+(j&3)
//       GEMM2 D: acc2[n][r] = C[m=rg*16+q*4+r][dout=n*16+lm]  (same epilogue as v7)
// Staging + swizzle byte-identical to HW-verified v5-v7.
__global__ __launch_bounds__(512, 4) void moe_gemm(
    const float* __restrict__ x, const unsigned short* __restrict__ w1T,
    const unsigned short* __restrict__ w2T, const int* __restrict__ counts,
    const int* __restrict__ rows, float* __restrict__ out) {
  int e = blockIdx.x;
  int cnt = counts[e];
  int base = blockIdx.y * TM;
  if (base >= cnt) return;

  // LDS: sW1[2][8192] | sW2[2][8192]  (65536 B, 2 blocks/CU)
  __shared__ __align__(16) unsigned short smem[32768];
  unsigned short* sW1 = smem;
  unsigned short* sW2 = smem + 16384;

  int tid = threadIdx.x;
  int wv = tid >> 6, l = tid & 63;
  int lm = l & 15, q = l >> 4;
  int rg = wv & 3;       // row group: rows [rg*16, rg*16+16)
  int hf = wv >> 2;      // H half:    h in [hf*32, hf*32+32) of each 64-chunk

  const unsigned short* w1e = w1T + (size_t)e * HH * DD;
  const unsigned short* w2e = w2T + (size_t)e * DD * HH;

  // X fragments in registers: xa[ks] holds X[m = base+rg*16+lm][d = ks*32 + q*8 + j]
  // (used as GEMM1's B-operand: col=lm=m, k=d -- same content as before)
  short8 xa[4];
  {
    int ridx = base + rg * 16 + lm; if (ridx >= cnt) ridx = cnt - 1;
    int grow = rows[e * NB + ridx];
    const float* xr = x + (size_t)grow * DD + q * 8;
    #pragma unroll
    for (int ks = 0; ks < 4; ++ks) {
      f32x4 v0 = *(const f32x4*)(xr + ks * 32);
      f32x4 v1 = *(const f32x4*)(xr + ks * 32 + 4);
      short8 a;
      a[0] = f2bf(v0[0]); a[1] = f2bf(v0[1]); a[2] = f2bf(v0[2]); a[3] = f2bf(v0[3]);
      a[4] = f2bf(v1[0]); a[5] = f2bf(v1[1]); a[6] = f2bf(v1[2]); a[7] = f2bf(v1[3]);
      xa[ks] = a;
    }
  }

  // direct-to-LDS staging: waves 0-3 own sW1 (4x 1KB DMA), waves 4-7 own sW2
  auto stage_chunk = [&](int buf, int c) {
    if (wv < 4) {
      const unsigned short* w1c = w1e + (size_t)c * HC * DD;
      #pragma unroll
      for (int i = 0; i < 4; ++i) {
        int r = wv * 16 + i * 4 + (l >> 4);
        const unsigned short* g = w1c + (size_t)r * DD + (((l & 15) ^ (r & 7)) << 3);
        __builtin_amdgcn_global_load_lds((gc_us*)g,
            (lds_us*)(sW1 + buf * 8192 + wv * 2048 + i * 512), 16, 0, 0);
      }
    } else {
      int wz = wv - 4;
      const unsigned short* w2c = w2e + (size_t)c * HC;
      #pragma unroll
      for (int i = 0; i < 4; ++i) {
        int r = wz * 32 + i * 8 + (l >> 3);
        const unsigned short* g = w2c + (size_t)r * HH + (((l & 7) ^ (r & 7)) << 3);
        __builtin_amdgcn_global_load_lds((gc_us*)g,
            (lds_us*)(sW2 + buf * 8192 + wz * 2048 + i * 512), 16, 0, 0);
      }
    }
  };

  stage_chunk(0, 0);
  __syncthreads();

  f32x4 acc2[8];
  #pragma unroll
  for (int n = 0; n < 8; ++n) acc2[n] = (f32x4){0.f, 0.f, 0.f, 0.f};

  for (int hc = 0; hc < NCH; ++hc) {
    int b = hc & 1;

    // next chunk's DMA flies under this chunk's compute
    if (hc + 1 < NCH) stage_chunk(b ^ 1, hc + 1);

    // GEMM1 (swapped): H^T(32h x 16m per wave) = W1chunk[hf-half] @ X^T
    f32x4 acc1[2];
    #pragma unroll
    for (int n = 0; n < 2; ++n) acc1[n] = (f32x4){0.f, 0.f, 0.f, 0.f};
    #pragma unroll
    for (int ks = 0; ks < 4; ++ks) {
      #pragma unroll
      for (int n = 0; n < 2; ++n) {
        int row = hf * 32 + n * 16 + lm;
        int sl = ((ks * 4 + q) ^ (row & 7)) * 8;
        short8 wfr = *(const short8*)&sW1[b * 8192 + row * DD + sl];
        acc1[n] = __builtin_amdgcn_mfma_f32_16x16x32_bf16(wfr, xa[ks], acc1[n], 0, 0, 0);
      }
    }
    // gelu + repack: fully lane-local (no LDS). ha[j] = gelu(acc1[j>>2][j&3])
    short8 ha;
    #pragma unroll
    for (int j = 0; j < 8; ++j) {
      float v = acc1[j >> 2][j & 3];
      float g = 0.5f * v * (1.0f + fast_erf(v * 0.70710678118654752f));
      ha[j] = (short)f2bf(g);
    }
    // GEMM2 partial: C(16m x 128d per wave) += gelu(H)[hf-half] @ W2 (sigma-permuted)
    #pragma unroll
    for (int n = 0; n < 8; ++n) {
      int row = n * 16 + lm;
      int sl = ((hf * 4 + q) ^ (row & 7)) * 8;
      short8 wfr = *(const short8*)&sW2[b * 8192 + row * HC + sl];
      acc2[n] = __builtin_amdgcn_mfma_f32_16x16x32_bf16(ha, wfr, acc2[n], 0, 0, 0);
    }

    __syncthreads();  // all waves done with buf b; next chunk's DMA drained
  }

  // ---- epilogue: sum hf-half partials via LDS (weights dead; reuse as fp32 scratch) ----
  float* sc = (float*)smem;   // [64][132] fp32 = 33792 B
  if (hf == 1) {
    #pragma unroll
    for (int n = 0; n < 8; ++n)
      #pragma unroll
      for (int rr = 0; rr < 4; ++rr)
        sc[(rg * 16 + q * 4 + rr) * 132 + n * 16 + lm] = acc2[n][rr];
  }
  __syncthreads();
  if (hf == 0) {
    #pragma unroll
    for (int rr = 0; rr < 4; ++rr) {
      int ml = rg * 16 + q * 4 + rr;
      int ridx = base + ml;
      if (ridx < cnt) {
        int grow = rows[e * NB + ridx];
        float* op = out + (size_t)grow * DD + lm;
        #pragma unroll
        for (int n = 0; n < 8; ++n)
          op[n * 16] = acc2[n][rr] + sc[(rg * 16 + q * 4 + rr) * 132 + n * 16 + lm];
      }
    }
  }
}

extern "C" void kernel_launch(void* const* d_in, const int* in_sizes, int n_in,
                              void* d_out, int out_size, void* d_ws, size_t ws_size,
                              hipStream_t stream) {
  const float* x  = (const float*)d_in[0];
  const float* w1 = (const float*)d_in[1];
  const float* w2 = (const float*)d_in[2];
  const float* wg = (const float*)d_in[3];
  const float* bg = (const float*)d_in[4];
  float* out = (float*)d_out;

  // workspace: [0,64) counts ; [1024, +2MB) rows ; w1T bf16 2MB ; w2T bf16 2MB
  int* counts = (int*)d_ws;
  int* rows   = (int*)((char*)d_ws + 1024);
  unsigned short* w1T = (unsigned short*)((char*)d_ws + 1024 + (size_t)EE * NB * 4);
  unsigned short* w2T = w1T + (size_t)EE * HH * DD;

  hipMemsetAsync(d_ws, 0, 64, stream);
  hipLaunchKernelGGL(prep_kernel, dim3(1024), dim3(256), 0, stream,
                     x, wg, bg, w1, w2, counts, rows, w1T, w2T);
  hipLaunchKernelGGL(moe_gemm, dim3(EE, NB / TM), dim3(512), 0, stream,
                     x, w1T, w2T, counts, rows, out);
}